// Round 16
// baseline (322.717 us; speedup 1.0000x reference)
//
#include <hip/hip_runtime.h>
#include <math.h>
#include <utility>
#include <type_traits>

namespace {

constexpr int C_  = 16;
constexpr int OR_ = 8;
constexpr int H_  = 192;
constexpr int W_  = 192;
constexpr int HW_ = H_ * W_;
constexpr int CH_ = OR_ * HW_;
constexpr float PI_F = 3.14159265358979323846f;

// Padded fp16 conv-output workspace: image px (y,x) -> padded (y+2, x+2).
constexpr int PH_  = 196;
constexpr int PW_  = 208;             // row = 416 B (16B multiple)
constexpr int PPL_ = PH_ * PW_;       // 40768 halves per plane
constexpr int NPL_ = C_ * OR_;        // 128 planes
constexpr int PAD_CELLS = 2 * PW_ + 2 * PW_ + H_ * 16;   // 3904 border cells/plane
constexpr int PAD_PER_BLOCK = 109;    // 36 tiles/plane * 109 >= 3904

constexpr int NBLK = 768;             // 3 blocks/CU, co-resident (launch_bounds enforced)

typedef _Float16 h4 __attribute__((ext_vector_type(4)));
typedef float f2u __attribute__((ext_vector_type(2), aligned(4)));
typedef _Float16 h2u __attribute__((ext_vector_type(2), aligned(2)));

constexpr float SQ2H = 0.70710678118654752440f;
constexpr float CT8[8] = { 1.0f,  SQ2H,  0.0f, -SQ2H, -1.0f, -SQ2H,  0.0f,  SQ2H };
constexpr float ST8[8] = { 0.0f,  SQ2H,  1.0f,  SQ2H,  0.0f, -SQ2H, -1.0f, -SQ2H };

constexpr int cfloor(float v) {
    return (v >= 0.0f) ? (int)v : (((float)(int)v == v) ? (int)v : (int)v - 1);
}

// Zero-padded corner fetch (matches reference _sample's per-corner validity).
template<typename SrcT>
__device__ __forceinline__ float cornerT(const SrcT* __restrict__ p, int iy, int ix) {
    bool valid = ((unsigned)iy < (unsigned)H_) && ((unsigned)ix < (unsigned)W_);
    int yc = min(max(iy, 0), H_ - 1);
    int xc = min(max(ix, 0), W_ - 1);
    float v = (float)p[yc * W_ + xc];
    return valid ? v : 0.0f;
}

template<typename SrcT>
__device__ __forceinline__ f2u pair2(const SrcT* __restrict__ p, int o) {
    if constexpr (std::is_same_v<SrcT, float>) {
        return *(const f2u*)(p + o);
    } else {
        const h2u h = *(const h2u*)(p + o);
        f2u r; r[0] = (float)h[0]; r[1] = (float)h[1];
        return r;
    }
}

// ---------------- grid barrier (monotone counter, device-scope atomics) -------
__device__ __forceinline__ void grid_barrier(unsigned* __restrict__ cnt, unsigned target) {
    __syncthreads();                       // drains vmcnt -> stores in L2 (XCD-local consumers)
    if (threadIdx.x == 0) {
        __hip_atomic_fetch_add(cnt, 1u, __ATOMIC_ACQ_REL, __HIP_MEMORY_SCOPE_AGENT);
        while (__hip_atomic_load(cnt, __ATOMIC_ACQUIRE, __HIP_MEMORY_SCOPE_AGENT) < target)
            __builtin_amdgcn_s_sleep(32);
    }
    __syncthreads();
}

// ---------------- conv work item (round-15 body) ------------------------------
// w in [0,576) per XCD: c = xcd + 8*(w/288); n = w%288; th = n/36; tile = n%36.
template<typename SrcT>
__device__ void conv_work(int w, int xcd, int t,
        const SrcT* __restrict__ u, const float* __restrict__ g0,
        _Float16* __restrict__ wsA) {
    const int cl = w / 288;
    const int c  = xcd + (cl << 3);
    const int n  = w - cl * 288;
    const int th   = n / 36;
    const int tile = n - th * 36;
    const int bx = tile % 3;
    const int by = tile / 3;
    const int z  = (c << 3) | th;

    const int tx  = t & 63;
    const int ty0 = (t >> 6) * 4;
    const int x   = bx * 64 + tx;
    const int y0  = by * 16 + ty0;

    // pad-border zeroing (36 tiles/plane x 109 cells, idempotent)
    {
        const int idx = tile * PAD_PER_BLOCK + t;
        if (t < PAD_PER_BLOCK && idx < PAD_CELLS) {
            int i = idx, r, col;
            if (i < 2 * PW_)      { r = i / PW_;            col = i % PW_; }
            else if (i < 4 * PW_) { i -= 2 * PW_; r = 194 + i / PW_; col = i % PW_; }
            else { i -= 4 * PW_; r = 2 + (i >> 4); const int cs = i & 15;
                   col = (cs < 2) ? cs : (192 + cs); }
            wsA[z * PPL_ + r * PW_ + col] = (_Float16)0.0f;
        }
    }

    const float gx0  = g0[c * 3 + 0];
    const float gy0  = g0[c * 3 + 1];
    const float gth0 = g0[c * 3 + 2];

    float sa, ca;
    sincosf((float)th * (2.0f * PI_F / OR_) - gth0, &sa, &ca);
    const float dxs = ca * gx0 - sa * gy0;
    const float dys = sa * gx0 + ca * gy0;

    const float fx = (float)x - dxs;
    const float fy = (float)y0 - dys;
    const float fx0 = floorf(fx), fy0 = floorf(fy);
    const float wx = fx - fx0, wy = fy - fy0;
    const int ix0 = (int)fx0, iy0 = (int)fy0;

    float tc = (float)th - gth0 * (OR_ / (2.0f * PI_F));
    tc = tc - floorf(tc * (1.0f / OR_)) * (float)OR_;
    const float t0f = floorf(tc);
    const float wt = tc - t0f;
    const int t0i = ((int)t0f) & 7;
    const int t1i = (t0i + 1) & 7;

    const SrcT* __restrict__ p0 = u + c * CH_ + t0i * HW_;
    const SrcT* __restrict__ p1 = u + c * CH_ + t1i * HW_;

    float r0, r1, r2, r3;
    if (ix0 >= 0 && ix0 + 1 < W_ && iy0 >= 0 && iy0 + 4 < H_) {
        const int o = iy0 * W_ + ix0;
        const f2u A0 = pair2(p0, o);
        const f2u A1 = pair2(p0, o + W_);
        const f2u A2 = pair2(p0, o + 2 * W_);
        const f2u A3 = pair2(p0, o + 3 * W_);
        const f2u A4 = pair2(p0, o + 4 * W_);
        const f2u B0 = pair2(p1, o);
        const f2u B1 = pair2(p1, o + W_);
        const f2u B2 = pair2(p1, o + 2 * W_);
        const f2u B3 = pair2(p1, o + 3 * W_);
        const f2u B4 = pair2(p1, o + 4 * W_);
        const float ha0 = A0[0] + wx * (A0[1] - A0[0]);
        const float ha1 = A1[0] + wx * (A1[1] - A1[0]);
        const float ha2 = A2[0] + wx * (A2[1] - A2[0]);
        const float ha3 = A3[0] + wx * (A3[1] - A3[0]);
        const float ha4 = A4[0] + wx * (A4[1] - A4[0]);
        const float hb0 = B0[0] + wx * (B0[1] - B0[0]);
        const float hb1 = B1[0] + wx * (B1[1] - B1[0]);
        const float hb2 = B2[0] + wx * (B2[1] - B2[0]);
        const float hb3 = B3[0] + wx * (B3[1] - B3[0]);
        const float hb4 = B4[0] + wx * (B4[1] - B4[0]);
        const float va0 = ha0 + wy * (ha1 - ha0);
        const float va1 = ha1 + wy * (ha2 - ha1);
        const float va2 = ha2 + wy * (ha3 - ha2);
        const float va3 = ha3 + wy * (ha4 - ha3);
        const float vb0 = hb0 + wy * (hb1 - hb0);
        const float vb1 = hb1 + wy * (hb2 - hb1);
        const float vb2 = hb2 + wy * (hb3 - hb2);
        const float vb3 = hb3 + wy * (hb4 - hb3);
        r0 = va0 + wt * (vb0 - va0);
        r1 = va1 + wt * (vb1 - va1);
        r2 = va2 + wt * (vb2 - va2);
        r3 = va3 + wt * (vb3 - va3);
    } else {
        const float w00 = (1.f - wy) * (1.f - wx);
        const float w01 = (1.f - wy) * wx;
        const float w10 = wy * (1.f - wx);
        const float w11 = wy * wx;
        float rr[4];
        #pragma unroll
        for (int j = 0; j < 4; ++j) {
            const int iy = iy0 + j;
            float v0 = w00 * cornerT(p0, iy, ix0)     + w01 * cornerT(p0, iy, ix0 + 1)
                     + w10 * cornerT(p0, iy + 1, ix0) + w11 * cornerT(p0, iy + 1, ix0 + 1);
            float v1 = w00 * cornerT(p1, iy, ix0)     + w01 * cornerT(p1, iy, ix0 + 1)
                     + w10 * cornerT(p1, iy + 1, ix0) + w11 * cornerT(p1, iy + 1, ix0 + 1);
            rr[j] = v0 + wt * (v1 - v0);
        }
        r0 = rr[0]; r1 = rr[1]; r2 = rr[2]; r3 = rr[3];
    }
    _Float16* __restrict__ op = wsA + z * PPL_ + (y0 + 2) * PW_ + (x + 2);
    op[0]       = (_Float16)r0;
    op[PW_]     = (_Float16)r1;
    op[2 * PW_] = (_Float16)r2;
    op[3 * PW_] = (_Float16)r3;
}

// ---------------- dilation (round-15 body) ------------------------------------
template<int TH, int PP, int OO>
__device__ __forceinline__ void off_one(const float (&w)[6][8],
        const float* __restrict__ sk, float (&ac0)[4], float (&ac1)[4]) {
    constexpr int hxi = OO % 3 - 1;
    constexpr int hyi = OO / 3 - 1;
    constexpr float ct = CT8[TH];
    constexpr float st = ST8[TH];
    constexpr float sx = ct * (float)hxi - st * (float)hyi;
    constexpr float sy = st * (float)hxi + ct * (float)hyi;
    constexpr int dx = cfloor(sx);
    constexpr int dy = cfloor(sy);
    constexpr float wx = sx - (float)dx;
    constexpr float wy = sy - (float)dy;
    constexpr int R  = dy + 2;
    constexpr int Cb = dx + 2;

    const float k = sk[PP * 9 + OO];
    #pragma unroll
    for (int j = 0; j < 4; ++j) {
        float v0, v1;
        if constexpr (wx == 0.0f && wy == 0.0f) {
            v0 = w[R][Cb + j];
            v1 = w[R + 1][Cb + j];
        } else if constexpr (wy == 0.0f) {
            const float a = w[R][Cb + j],     a1 = w[R][Cb + j + 1];
            const float b = w[R + 1][Cb + j], b1 = w[R + 1][Cb + j + 1];
            v0 = a + wx * (a1 - a);
            v1 = b + wx * (b1 - b);
        } else if constexpr (wx == 0.0f) {
            const float a  = w[R][Cb + j];
            const float b  = w[R + 1][Cb + j];
            const float cc = w[R + 2][Cb + j];
            v0 = a + wy * (b - a);
            v1 = b + wy * (cc - b);
        } else {
            const float a  = w[R][Cb + j],     a1  = w[R][Cb + j + 1];
            const float b  = w[R + 1][Cb + j], b1  = w[R + 1][Cb + j + 1];
            const float cc = w[R + 2][Cb + j], cc1 = w[R + 2][Cb + j + 1];
            const float h0 = a  + wx * (a1 - a);
            const float h1 = b  + wx * (b1 - b);
            const float h2 = cc + wx * (cc1 - cc);
            v0 = h0 + wy * (h1 - h0);
            v1 = h1 + wy * (h2 - h1);
        }
        ac0[j] = fmaxf(ac0[j], v0 - k);
        ac1[j] = fmaxf(ac1[j], v1 - k);
    }
}

template<int TH, int PP, int... OOs>
__device__ __forceinline__ void off_nine(std::integer_sequence<int, OOs...>,
        const float (&w)[6][8], const float* __restrict__ sk,
        float (&ac0)[4], float (&ac1)[4]) {
    (off_one<TH, PP, OOs>(w, sk, ac0, ac1), ...);
}

template<int TH, int PP>
__device__ __forceinline__ void do_plane(const _Float16* __restrict__ wb,
        const float* __restrict__ sk, float (&ac0)[4], float (&ac1)[4]) {
    constexpr int plane = (TH + PP - 1 + OR_) & 7;
    float w[6][8];
    const _Float16* __restrict__ base = wb + plane * PPL_;
    #pragma unroll
    for (int r = 0; r < 6; ++r) {
        const h4 lo = *(const h4*)&base[r * PW_];
        const h4 hi = *(const h4*)&base[r * PW_ + 4];
        #pragma unroll
        for (int j = 0; j < 4; ++j) {
            w[r][j]     = (float)lo[j];
            w[r][4 + j] = (float)hi[j];
        }
    }
    off_nine<TH, PP>(std::make_integer_sequence<int, 9>{}, w, sk, ac0, ac1);
}

template<int TH>
__device__ __forceinline__ void dil_theta(const _Float16* __restrict__ wb,
        const float* __restrict__ sk, float (&ac0)[4], float (&ac1)[4]) {
    do_plane<TH, 0>(wb, sk, ac0, ac1);
    do_plane<TH, 1>(wb, sk, ac0, ac1);
    do_plane<TH, 2>(wb, sk, ac0, ac1);
}

// w in [0,288) per XCD: cl = w/144; c = xcd+8*cl; n = w%144; th = n/18; tile = n%18.
template<typename DstT>
__device__ void dil_work(int w, int xcd, int t,
        const _Float16* __restrict__ wsA, const float (*__restrict__ s_k2)[27],
        DstT* __restrict__ out) {
    const int cl = w / 144;
    const int c  = xcd + (cl << 3);
    const int n  = w - cl * 144;
    const int th   = n / 18;
    const int tile = n - th * 18;
    const int bx = tile % 3;
    const int by = tile / 3;

    const int xg = t & 15;
    const int ry = t >> 4;
    const int gx = bx * 64 + xg * 4;
    const int gy = by * 32 + ry * 2;

    const _Float16* __restrict__ wb = wsA + c * OR_ * PPL_ + gy * PW_ + gx;
    const float* __restrict__ sk = s_k2[cl];

    float ac0[4], ac1[4];
    #pragma unroll
    for (int j = 0; j < 4; ++j) { ac0[j] = -INFINITY; ac1[j] = -INFINITY; }

    switch (th) {
        case 0: dil_theta<0>(wb, sk, ac0, ac1); break;
        case 1: dil_theta<1>(wb, sk, ac0, ac1); break;
        case 2: dil_theta<2>(wb, sk, ac0, ac1); break;
        case 3: dil_theta<3>(wb, sk, ac0, ac1); break;
        case 4: dil_theta<4>(wb, sk, ac0, ac1); break;
        case 5: dil_theta<5>(wb, sk, ac0, ac1); break;
        case 6: dil_theta<6>(wb, sk, ac0, ac1); break;
        case 7: dil_theta<7>(wb, sk, ac0, ac1); break;
        default: __builtin_unreachable();
    }

    const int o = c * CH_ + th * HW_ + gy * W_ + gx;
    if constexpr (std::is_same_v<DstT, float>) {
        float4 r0, r1;
        r0.x = ac0[0]; r0.y = ac0[1]; r0.z = ac0[2]; r0.w = ac0[3];
        r1.x = ac1[0]; r1.y = ac1[1]; r1.z = ac1[2]; r1.w = ac1[3];
        *(float4*)&out[o] = r0;
        *(float4*)&out[o + W_] = r1;
    } else {
        h4 r0, r1;
        r0[0] = (_Float16)ac0[0]; r0[1] = (_Float16)ac0[1];
        r0[2] = (_Float16)ac0[2]; r0[3] = (_Float16)ac0[3];
        r1[0] = (_Float16)ac1[0]; r1[1] = (_Float16)ac1[1];
        r1[2] = (_Float16)ac1[2]; r1[3] = (_Float16)ac1[3];
        *(h4*)&out[o] = r0;
        *(h4*)&out[o + W_] = r1;
    }
}

// ---------------- persistent 4-phase pipeline, 768 blocks, XCD-pinned ---------
__global__ __launch_bounds__(256, 3) void pipeline_kernel(
        const float* __restrict__ u, const float* __restrict__ g0,
        const float* __restrict__ mp, _Float16* __restrict__ wsA,
        _Float16* __restrict__ wsB, float* __restrict__ out,
        unsigned* __restrict__ cnt) {
    __shared__ float s_k2[2][27];

    const int b = blockIdx.x;
    const int xcd = b & 7;
    const int l   = b >> 3;            // 0..95 (per-XCD block index)
    const int t = threadIdx.x;

    // k-tables for this XCD's two channels (c = xcd, xcd+8)
    if (t < 54) {
        const int cl = t / 27, o = t - cl * 27;
        const int c = xcd + (cl << 3);
        const int hti = o / 9 - 1;
        const int hyi = (o / 3) % 3 - 1;
        const int hxi = o % 3 - 1;
        const float hx = (float)hxi, hy = (float)hyi;
        const float hth  = (float)hti * (2.0f * PI_F / OR_);
        const float half = 0.5f * hth;
        float q;
        if (fabsf(half) < 1e-4f) q = 1.0f - half * half * (1.0f / 3.0f);
        else                     q = half / tanf(half);
        const float c1 = q * hx + half * hy;
        const float c2 = -half * hx + q * hy;
        const float c3 = hth;
        const float m0 = mp[c * 3 + 0], m1 = mp[c * 3 + 1], m2 = mp[c * 3 + 2];
        const float d2 = (m0 * c1) * (m0 * c1) + (m1 * c2) * (m1 * c2) + (m2 * c3) * (m2 * c3);
        const float ee = 2.0f * 0.65f / (2.0f * 0.65f - 1.0f);
        const float nu = (2.0f * 0.65f - 1.0f) * powf(2.0f * 0.65f, -ee);
        s_k2[cl][o] = nu * powf(d2, 0.5f * ee);
    }
    __syncthreads();

    // phase 1: conv(u) -> wsA
    #pragma unroll 1
    for (int i = 0; i < 6; ++i) conv_work<float>(l * 6 + i, xcd, t, u, g0, wsA);
    grid_barrier(cnt, NBLK);

    // phase 2: dil(wsA) -> wsB
    #pragma unroll 1
    for (int i = 0; i < 3; ++i) dil_work<_Float16>(l * 3 + i, xcd, t, wsA, s_k2, wsB);
    grid_barrier(cnt, 2 * NBLK);

    // phase 3: conv(wsB) -> wsA
    #pragma unroll 1
    for (int i = 0; i < 6; ++i) conv_work<_Float16>(l * 6 + i, xcd, t, wsB, g0, wsA);
    grid_barrier(cnt, 3 * NBLK);

    // phase 4: dil(wsA) -> out
    #pragma unroll 1
    for (int i = 0; i < 3; ++i) dil_work<float>(l * 3 + i, xcd, t, wsA, s_k2, out);
}

} // anonymous namespace

extern "C" void kernel_launch(void* const* d_in, const int* in_sizes, int n_in,
                              void* d_out, int out_size, void* d_ws, size_t ws_size,
                              hipStream_t stream) {
    const float* u   = (const float*)d_in[0];
    const float* g0  = (const float*)d_in[1];
    const float* mpp = (const float*)d_in[2];
    float* out = (float*)d_out;
    _Float16* wsA = (_Float16*)d_ws;                 // padded fp16 conv output, 10.4 MB
    _Float16* wsB = wsA + NPL_ * PPL_;               // fp16 dil-1 output, 9.4 MB
    // barrier counter after wsA+wsB (ws_size >= 39 MB per round-9 usage), 64B-aligned
    size_t cnt_off = ((size_t)NPL_ * PPL_ * 2 * sizeof(_Float16) + 63) & ~(size_t)63;
    unsigned* cnt = (unsigned*)((char*)d_ws + cnt_off);

    hipMemsetAsync(cnt, 0, 64, stream);
    pipeline_kernel<<<dim3(NBLK), dim3(256), 0, stream>>>(u, g0, mpp, wsA, wsB, out, cnt);
}

// Round 17
// 49.251 us; speedup vs baseline: 6.5525x; 6.5525x over previous
//
#include <hip/hip_runtime.h>
#include <math.h>
#include <utility>
#include <type_traits>

namespace {

constexpr int C_  = 16;
constexpr int OR_ = 8;
constexpr int H_  = 192;
constexpr int W_  = 192;
constexpr int HW_ = H_ * W_;
constexpr int CH_ = OR_ * HW_;
constexpr float PI_F = 3.14159265358979323846f;

// Padded fp16 conv-output workspace: image px (y,x) -> padded (y+2, x+2).
constexpr int PH_  = 196;
constexpr int PW_  = 208;             // row = 416 B (16B multiple)
constexpr int PPL_ = PH_ * PW_;       // 40768 halves per plane
constexpr int NPL_ = C_ * OR_;        // 128 planes
constexpr int PAD_CELLS = 2 * PW_ + 2 * PW_ + H_ * 16;   // 3904 border cells/plane
constexpr int PAD_PER_BLOCK = 109;    // 36 blocks/plane * 109 >= 3904

typedef _Float16 h2 __attribute__((ext_vector_type(2)));
typedef _Float16 h4 __attribute__((ext_vector_type(4)));
typedef float f2u __attribute__((ext_vector_type(2), aligned(4)));
typedef _Float16 h2u __attribute__((ext_vector_type(2), aligned(2)));
typedef unsigned int uint2v __attribute__((ext_vector_type(2), aligned(8)));

constexpr float SQ2H = 0.70710678118654752440f;
constexpr float CT8[8] = { 1.0f,  SQ2H,  0.0f, -SQ2H, -1.0f, -SQ2H,  0.0f,  SQ2H };
constexpr float ST8[8] = { 0.0f,  SQ2H,  1.0f,  SQ2H,  0.0f, -SQ2H, -1.0f, -SQ2H };

constexpr int cfloor(float v) {
    return (v >= 0.0f) ? (int)v : (((float)(int)v == v) ? (int)v : (int)v - 1);
}

// Zero-padded corner fetch (matches reference _sample's per-corner validity).
template<typename SrcT>
__device__ __forceinline__ float cornerT(const SrcT* __restrict__ p, int iy, int ix) {
    bool valid = ((unsigned)iy < (unsigned)H_) && ((unsigned)ix < (unsigned)W_);
    int yc = min(max(iy, 0), H_ - 1);
    int xc = min(max(ix, 0), W_ - 1);
    float v = (float)p[yc * W_ + xc];
    return valid ? v : 0.0f;
}

template<typename SrcT>
__device__ __forceinline__ f2u pair2(const SrcT* __restrict__ p, int o) {
    if constexpr (std::is_same_v<SrcT, float>) {
        return *(const f2u*)(p + o);
    } else {
        const h2u h = *(const h2u*)(p + o);
        f2u r; r[0] = (float)h[0]; r[1] = (float)h[1];
        return r;
    }
}

// ---------------- convection_m2 (round-15 verbatim, XCD-pinned 1-D grid) ------
// block id = (n<<4)|c, n = th*36 + tile  ->  id%8 == c%8  (channel->XCD pin)
template<typename SrcT>
__global__ __launch_bounds__(256) void conv_kernel(
        const SrcT* __restrict__ u, const float* __restrict__ g0,
        _Float16* __restrict__ wsA) {
    const int id = blockIdx.x;
    const int c    = id & 15;
    const int n    = id >> 4;          // 0..287
    const int th   = n / 36;
    const int tile = n - th * 36;      // 0..35
    const int bx   = tile % 3;
    const int by   = tile / 3;         // 0..11
    const int z    = (c << 3) | th;

    const int t = threadIdx.x;
    const int tx  = t & 63;
    const int ty0 = (t >> 6) * 4;
    const int x   = bx * 64 + tx;
    const int y0  = by * 16 + ty0;

    // ---- pad-border zeroing (36 blocks/plane x 109 cells) ----
    {
        const int idx = tile * PAD_PER_BLOCK + t;
        if (t < PAD_PER_BLOCK && idx < PAD_CELLS) {
            int i = idx, r, col;
            if (i < 2 * PW_)      { r = i / PW_;            col = i % PW_; }
            else if (i < 4 * PW_) { i -= 2 * PW_; r = 194 + i / PW_; col = i % PW_; }
            else { i -= 4 * PW_; r = 2 + (i >> 4); const int cs = i & 15;
                   col = (cs < 2) ? cs : (192 + cs); }
            wsA[z * PPL_ + r * PW_ + col] = (_Float16)0.0f;
        }
    }

    const float gx0  = g0[c * 3 + 0];
    const float gy0  = g0[c * 3 + 1];
    const float gth0 = g0[c * 3 + 2];

    float sa, ca;
    sincosf((float)th * (2.0f * PI_F / OR_) - gth0, &sa, &ca);
    const float dxs = ca * gx0 - sa * gy0;
    const float dys = sa * gx0 + ca * gy0;

    const float fx = (float)x - dxs;
    const float fy = (float)y0 - dys;
    const float fx0 = floorf(fx), fy0 = floorf(fy);
    const float wx = fx - fx0, wy = fy - fy0;
    const int ix0 = (int)fx0, iy0 = (int)fy0;

    float tc = (float)th - gth0 * (OR_ / (2.0f * PI_F));
    tc = tc - floorf(tc * (1.0f / OR_)) * (float)OR_;
    const float t0f = floorf(tc);
    const float wt = tc - t0f;
    const int t0i = ((int)t0f) & 7;
    const int t1i = (t0i + 1) & 7;

    const SrcT* __restrict__ p0 = u + c * CH_ + t0i * HW_;
    const SrcT* __restrict__ p1 = u + c * CH_ + t1i * HW_;

    float r0, r1, r2, r3;
    if (ix0 >= 0 && ix0 + 1 < W_ && iy0 >= 0 && iy0 + 4 < H_) {
        const int o = iy0 * W_ + ix0;
        const f2u A0 = pair2(p0, o);
        const f2u A1 = pair2(p0, o + W_);
        const f2u A2 = pair2(p0, o + 2 * W_);
        const f2u A3 = pair2(p0, o + 3 * W_);
        const f2u A4 = pair2(p0, o + 4 * W_);
        const f2u B0 = pair2(p1, o);
        const f2u B1 = pair2(p1, o + W_);
        const f2u B2 = pair2(p1, o + 2 * W_);
        const f2u B3 = pair2(p1, o + 3 * W_);
        const f2u B4 = pair2(p1, o + 4 * W_);
        const float ha0 = A0[0] + wx * (A0[1] - A0[0]);
        const float ha1 = A1[0] + wx * (A1[1] - A1[0]);
        const float ha2 = A2[0] + wx * (A2[1] - A2[0]);
        const float ha3 = A3[0] + wx * (A3[1] - A3[0]);
        const float ha4 = A4[0] + wx * (A4[1] - A4[0]);
        const float hb0 = B0[0] + wx * (B0[1] - B0[0]);
        const float hb1 = B1[0] + wx * (B1[1] - B1[0]);
        const float hb2 = B2[0] + wx * (B2[1] - B2[0]);
        const float hb3 = B3[0] + wx * (B3[1] - B3[0]);
        const float hb4 = B4[0] + wx * (B4[1] - B4[0]);
        const float va0 = ha0 + wy * (ha1 - ha0);
        const float va1 = ha1 + wy * (ha2 - ha1);
        const float va2 = ha2 + wy * (ha3 - ha2);
        const float va3 = ha3 + wy * (ha4 - ha3);
        const float vb0 = hb0 + wy * (hb1 - hb0);
        const float vb1 = hb1 + wy * (hb2 - hb1);
        const float vb2 = hb2 + wy * (hb3 - hb2);
        const float vb3 = hb3 + wy * (hb4 - hb3);
        r0 = va0 + wt * (vb0 - va0);
        r1 = va1 + wt * (vb1 - va1);
        r2 = va2 + wt * (vb2 - va2);
        r3 = va3 + wt * (vb3 - va3);
    } else {
        const float w00 = (1.f - wy) * (1.f - wx);
        const float w01 = (1.f - wy) * wx;
        const float w10 = wy * (1.f - wx);
        const float w11 = wy * wx;
        float rr[4];
        #pragma unroll
        for (int j = 0; j < 4; ++j) {
            const int iy = iy0 + j;
            float v0 = w00 * cornerT(p0, iy, ix0)     + w01 * cornerT(p0, iy, ix0 + 1)
                     + w10 * cornerT(p0, iy + 1, ix0) + w11 * cornerT(p0, iy + 1, ix0 + 1);
            float v1 = w00 * cornerT(p1, iy, ix0)     + w01 * cornerT(p1, iy, ix0 + 1)
                     + w10 * cornerT(p1, iy + 1, ix0) + w11 * cornerT(p1, iy + 1, ix0 + 1);
            rr[j] = v0 + wt * (v1 - v0);
        }
        r0 = rr[0]; r1 = rr[1]; r2 = rr[2]; r3 = rr[3];
    }
    _Float16* __restrict__ op = wsA + z * PPL_ + (y0 + 2) * PW_ + (x + 2);
    op[0]       = (_Float16)r0;
    op[PW_]     = (_Float16)r1;
    op[2 * PW_] = (_Float16)r2;
    op[3 * PW_] = (_Float16)r3;
}

// ---------------- dilation: packed fp16 4x2-px register windows ---------------
// Window rows r=0..5 (global gy-2..gy+3), cols 0..7 (global gx-2..gx+5).
// E[r][i] = dword of cols {2i,2i+1}; O[r][i] = dword of cols {2i+1,2i+2}.
struct h2x2 { h2 a, b; };

template<int R, int S>
__device__ __forceinline__ h2x2 getv(const unsigned (&E)[6][4], const unsigned (&O)[6][3]) {
    if constexpr ((S & 1) == 0) {
        return { __builtin_bit_cast(h2, E[R][S / 2]), __builtin_bit_cast(h2, E[R][S / 2 + 1]) };
    } else {
        return { __builtin_bit_cast(h2, O[R][S / 2]), __builtin_bit_cast(h2, O[R][S / 2 + 1]) };
    }
}

template<int TH, int PP, int OO>
__device__ __forceinline__ void off_one(const unsigned (&E)[6][4], const unsigned (&O)[6][3],
        const float* __restrict__ sk, h2 (&ac0)[2], h2 (&ac1)[2]) {
    constexpr int hxi = OO % 3 - 1;
    constexpr int hyi = OO / 3 - 1;
    constexpr float ct = CT8[TH];
    constexpr float st = ST8[TH];
    constexpr float sx = ct * (float)hxi - st * (float)hyi;
    constexpr float sy = st * (float)hxi + ct * (float)hyi;
    constexpr int dx = cfloor(sx);
    constexpr int dy = cfloor(sy);
    constexpr float wx = sx - (float)dx;
    constexpr float wy = sy - (float)dy;
    constexpr int R  = dy + 2;    // 0..3
    constexpr int Cb = dx + 2;    // 0..3

    const _Float16 kh = (_Float16)sk[PP * 9 + OO];
    const h2 kv = { kh, kh };

    h2 v0a, v0b, v1a, v1b;
    if constexpr (wx == 0.0f && wy == 0.0f) {
        const h2x2 r0 = getv<R, Cb>(E, O);
        const h2x2 r1 = getv<R + 1, Cb>(E, O);
        v0a = r0.a; v0b = r0.b;
        v1a = r1.a; v1b = r1.b;
    } else if constexpr (wy == 0.0f) {
        const _Float16 wxh = (_Float16)wx;
        const h2 wxv = { wxh, wxh };
        const h2x2 a  = getv<R, Cb>(E, O);
        const h2x2 a1 = getv<R, Cb + 1>(E, O);
        const h2x2 b  = getv<R + 1, Cb>(E, O);
        const h2x2 b1 = getv<R + 1, Cb + 1>(E, O);
        v0a = a.a + wxv * (a1.a - a.a);
        v0b = a.b + wxv * (a1.b - a.b);
        v1a = b.a + wxv * (b1.a - b.a);
        v1b = b.b + wxv * (b1.b - b.b);
    } else if constexpr (wx == 0.0f) {
        const _Float16 wyh = (_Float16)wy;
        const h2 wyv = { wyh, wyh };
        const h2x2 a = getv<R, Cb>(E, O);
        const h2x2 b = getv<R + 1, Cb>(E, O);
        const h2x2 c = getv<R + 2, Cb>(E, O);
        v0a = a.a + wyv * (b.a - a.a);
        v0b = a.b + wyv * (b.b - a.b);
        v1a = b.a + wyv * (c.a - b.a);
        v1b = b.b + wyv * (c.b - b.b);
    } else {
        const _Float16 wxh = (_Float16)wx;
        const _Float16 wyh = (_Float16)wy;
        const h2 wxv = { wxh, wxh };
        const h2 wyv = { wyh, wyh };
        const h2x2 a  = getv<R, Cb>(E, O);
        const h2x2 a1 = getv<R, Cb + 1>(E, O);
        const h2x2 b  = getv<R + 1, Cb>(E, O);
        const h2x2 b1 = getv<R + 1, Cb + 1>(E, O);
        const h2x2 c  = getv<R + 2, Cb>(E, O);
        const h2x2 c1 = getv<R + 2, Cb + 1>(E, O);
        const h2 h0a = a.a + wxv * (a1.a - a.a);
        const h2 h0b = a.b + wxv * (a1.b - a.b);
        const h2 h1a = b.a + wxv * (b1.a - b.a);   // shared by both rows
        const h2 h1b = b.b + wxv * (b1.b - b.b);
        const h2 h2a = c.a + wxv * (c1.a - c.a);
        const h2 h2b = c.b + wxv * (c1.b - c.b);
        v0a = h0a + wyv * (h1a - h0a);
        v0b = h0b + wyv * (h1b - h0b);
        v1a = h1a + wyv * (h2a - h1a);
        v1b = h1b + wyv * (h2b - h1b);
    }
    ac0[0] = __builtin_elementwise_max(ac0[0], v0a - kv);
    ac0[1] = __builtin_elementwise_max(ac0[1], v0b - kv);
    ac1[0] = __builtin_elementwise_max(ac1[0], v1a - kv);
    ac1[1] = __builtin_elementwise_max(ac1[1], v1b - kv);
}

template<int TH, int PP, int... OOs>
__device__ __forceinline__ void off_nine(std::integer_sequence<int, OOs...>,
        const unsigned (&E)[6][4], const unsigned (&O)[6][3],
        const float* __restrict__ sk, h2 (&ac0)[2], h2 (&ac1)[2]) {
    (off_one<TH, PP, OOs>(E, O, sk, ac0, ac1), ...);
}

// Plane slot PP (hti = PP-1): 12 x 8B loads -> packed window + 18 alignbits.
template<int TH, int PP>
__device__ __forceinline__ void do_plane(const _Float16* __restrict__ wb,
        const float* __restrict__ sk, h2 (&ac0)[2], h2 (&ac1)[2]) {
    constexpr int plane = (TH + PP - 1 + OR_) & 7;
    unsigned E[6][4];
    unsigned O[6][3];
    const _Float16* __restrict__ base = wb + plane * PPL_;
    #pragma unroll
    for (int r = 0; r < 6; ++r) {
        const uint2v lo = *(const uint2v*)&base[r * PW_];
        const uint2v hi = *(const uint2v*)&base[r * PW_ + 4];
        E[r][0] = lo[0]; E[r][1] = lo[1]; E[r][2] = hi[0]; E[r][3] = hi[1];
        O[r][0] = (E[r][0] >> 16) | (E[r][1] << 16);
        O[r][1] = (E[r][1] >> 16) | (E[r][2] << 16);
        O[r][2] = (E[r][2] >> 16) | (E[r][3] << 16);
    }
    off_nine<TH, PP>(std::make_integer_sequence<int, 9>{}, E, O, sk, ac0, ac1);
}

template<int TH>
__device__ __forceinline__ void dil_theta(const _Float16* __restrict__ wb,
        const float* __restrict__ sk, h2 (&ac0)[2], h2 (&ac1)[2]) {
    do_plane<TH, 0>(wb, sk, ac0, ac1);
    do_plane<TH, 1>(wb, sk, ac0, ac1);
    do_plane<TH, 2>(wb, sk, ac0, ac1);
}

// block id = (n<<4)|c, n = th*18 + tile  ->  id%8 == c%8  (channel->XCD pin)
template<typename DstT>
__global__ __launch_bounds__(256) void dil_kernel(
        const _Float16* __restrict__ wsA, const float* __restrict__ mp,
        DstT* __restrict__ out) {
    __shared__ float s_k[27];

    const int id = blockIdx.x;
    const int c    = id & 15;
    const int n    = id >> 4;          // 0..143
    const int th   = n / 18;
    const int tile = n - th * 18;      // 0..17
    const int bx   = tile % 3;
    const int by   = tile / 3;         // 0..5
    const int t = threadIdx.x;

    if (t < 27) {
        const int hti = t / 9 - 1;
        const int hyi = (t / 3) % 3 - 1;
        const int hxi = t % 3 - 1;
        const float hx = (float)hxi, hy = (float)hyi;
        const float hth  = (float)hti * (2.0f * PI_F / OR_);
        const float half = 0.5f * hth;
        float q;
        if (fabsf(half) < 1e-4f) q = 1.0f - half * half * (1.0f / 3.0f);
        else                     q = half / tanf(half);
        const float c1 = q * hx + half * hy;
        const float c2 = -half * hx + q * hy;
        const float c3 = hth;
        const float m0 = mp[c * 3 + 0], m1 = mp[c * 3 + 1], m2 = mp[c * 3 + 2];
        const float d2 = (m0 * c1) * (m0 * c1) + (m1 * c2) * (m1 * c2) + (m2 * c3) * (m2 * c3);
        const float ee = 2.0f * 0.65f / (2.0f * 0.65f - 1.0f);
        const float nu = (2.0f * 0.65f - 1.0f) * powf(2.0f * 0.65f, -ee);
        s_k[t] = nu * powf(d2, 0.5f * ee);
    }
    __syncthreads();

    const int xg = t & 15;                       // 4 px: gx..gx+3
    const int ry = t >> 4;                       // 0..15, 2 rows each
    const int gx = bx * 64 + xg * 4;
    const int gy = by * 32 + ry * 2;

    // window base: padded (gy, gx) == image (gy-2, gx-2); 8B aligned (gx%4==0)
    const _Float16* __restrict__ wb = wsA + c * OR_ * PPL_ + gy * PW_ + gx;

    const h2 ninf = __builtin_bit_cast(h2, 0xFC00FC00u);   // {-inf, -inf} fp16
    h2 ac0[2] = { ninf, ninf };
    h2 ac1[2] = { ninf, ninf };

    switch (th) {
        case 0: dil_theta<0>(wb, s_k, ac0, ac1); break;
        case 1: dil_theta<1>(wb, s_k, ac0, ac1); break;
        case 2: dil_theta<2>(wb, s_k, ac0, ac1); break;
        case 3: dil_theta<3>(wb, s_k, ac0, ac1); break;
        case 4: dil_theta<4>(wb, s_k, ac0, ac1); break;
        case 5: dil_theta<5>(wb, s_k, ac0, ac1); break;
        case 6: dil_theta<6>(wb, s_k, ac0, ac1); break;
        case 7: dil_theta<7>(wb, s_k, ac0, ac1); break;
        default: __builtin_unreachable();
    }

    const int o = c * CH_ + th * HW_ + gy * W_ + gx;
    if constexpr (std::is_same_v<DstT, float>) {
        float4 r0, r1;
        r0.x = (float)ac0[0][0]; r0.y = (float)ac0[0][1];
        r0.z = (float)ac0[1][0]; r0.w = (float)ac0[1][1];
        r1.x = (float)ac1[0][0]; r1.y = (float)ac1[0][1];
        r1.z = (float)ac1[1][0]; r1.w = (float)ac1[1][1];
        *(float4*)&out[o] = r0;
        *(float4*)&out[o + W_] = r1;
    } else {
        h4 r0, r1;
        r0[0] = ac0[0][0]; r0[1] = ac0[0][1]; r0[2] = ac0[1][0]; r0[3] = ac0[1][1];
        r1[0] = ac1[0][0]; r1[1] = ac1[0][1]; r1[2] = ac1[1][0]; r1[3] = ac1[1][1];
        *(h4*)&out[o] = r0;
        *(h4*)&out[o + W_] = r1;
    }
}

} // anonymous namespace

extern "C" void kernel_launch(void* const* d_in, const int* in_sizes, int n_in,
                              void* d_out, int out_size, void* d_ws, size_t ws_size,
                              hipStream_t stream) {
    const float* u   = (const float*)d_in[0];
    const float* g0  = (const float*)d_in[1];
    const float* mpp = (const float*)d_in[2];
    float* out = (float*)d_out;
    _Float16* wsA = (_Float16*)d_ws;                 // padded fp16 conv output, 10.4 MB
    _Float16* wsB = wsA + NPL_ * PPL_;               // fp16 dil-1 output, 9.4 MB

    dim3 cgrid(288 * 16);                            // conv: 4608 blocks, 1-D XCD-pinned
    dim3 dgrid(144 * 16);                            // dil:  2304 blocks, 1-D XCD-pinned
    dim3 block(256);

    // iter 1
    conv_kernel<float>   <<<cgrid, block, 0, stream>>>(u,   g0,  wsA);
    dil_kernel<_Float16> <<<dgrid, block, 0, stream>>>(wsA, mpp, wsB);
    // iter 2
    conv_kernel<_Float16><<<cgrid, block, 0, stream>>>(wsB, g0,  wsA);
    dil_kernel<float>    <<<dgrid, block, 0, stream>>>(wsA, mpp, out);
}